// Round 15
// baseline (258.829 us; speedup 1.0000x reference)
//
#include <hip/hip_runtime.h>
#include <hip/hip_bf16.h>
#include <stdint.h>
#include <math.h>

#define B_ 4
#define T_ 2048
#define E_ 1024
#define H_ 16
#define D_ 64

typedef __attribute__((ext_vector_type(8))) short short8;
typedef __attribute__((ext_vector_type(4))) short short4v;
typedef __attribute__((ext_vector_type(4))) float f32x4;

#define MFMA_BF16(a, b, c) __builtin_amdgcn_mfma_f32_16x16x32_bf16((a), (b), (c), 0, 0, 0)

__device__ __forceinline__ unsigned short f2bf(float f) {
  union { float f; unsigned u; } v; v.f = f;
  unsigned r = v.u + 0x7FFFu + ((v.u >> 16) & 1u);  // RNE
  return (unsigned short)(r >> 16);
}

#define GLOAD_LDS16(g, l)                                                        \
  __builtin_amdgcn_global_load_lds((const __attribute__((address_space(1))) void*)(g), \
                                   (__attribute__((address_space(3))) void*)(l), 16, 0, 0)

// ---------------- fp32 -> bf16 convert: x + 4 weights in ONE launch ----------
__global__ __launch_bounds__(256) void cvt_all(const float* __restrict__ x,
                                               const float* __restrict__ w0,
                                               const float* __restrict__ w1,
                                               const float* __restrict__ w2,
                                               const float* __restrict__ w3,
                                               unsigned short* __restrict__ xb,
                                               unsigned short* __restrict__ wb) {
  const int NX8 = 1048576;  // XE/8
  int i = blockIdx.x * blockDim.x + threadIdx.x;
  const float* src;
  unsigned short* dst;
  size_t off;
  if (i < NX8) {
    src = x; dst = xb; off = (size_t)i * 8;
  } else {
    int j = i - NX8;                 // 0 .. 4*WE/8-1
    int which = j >> 17;             // WE/8 = 2^17
    int o = j & 131071;
    src = (which == 0) ? w0 : (which == 1) ? w1 : (which == 2) ? w2 : w3;
    dst = wb + ((size_t)which << 20);
    off = (size_t)o * 8;
  }
  const float4* p = (const float4*)(src + off);
  float4 a = p[0], b = p[1];
  short8 r;
  r[0] = (short)f2bf(a.x); r[1] = (short)f2bf(a.y);
  r[2] = (short)f2bf(a.z); r[3] = (short)f2bf(a.w);
  r[4] = (short)f2bf(b.x); r[5] = (short)f2bf(b.y);
  r[6] = (short)f2bf(b.z); r[7] = (short)f2bf(b.w);
  *(short8*)(dst + off) = r;
}

// ---------------- fused QKV GEMM (XCD-swizzled 1D grid, 1536 blocks) ---------
// xcd = bid%8 owns bx in [xcd*8, xcd*8+8): each A-row-panel's 24 consumer
// blocks land on ONE XCD -> A panel fetched into one L2, not eight.
// sel 0/1 (Q,K): bf16 [B*H][T][D]. sel 2 (V): bf16 TRANSPOSED [B*H][D][T].
__global__ __launch_bounds__(256) void gemm_qkv(const unsigned short* __restrict__ A,
                                                const unsigned short* __restrict__ Wq,
                                                const unsigned short* __restrict__ Wk,
                                                const unsigned short* __restrict__ Wv,
                                                unsigned short* __restrict__ Qo,
                                                unsigned short* __restrict__ Ko,
                                                unsigned short* __restrict__ Vo) {
  __shared__ __align__(16) unsigned short Ab[128 * 64];
  __shared__ __align__(16) unsigned short Bb[128 * 64];
  const int K = E_;
  const int tid = threadIdx.x;
  const int wid = tid >> 6;
  const int lr = tid & 15;
  const int lk = (tid >> 4) & 3;
  const int wr = wid >> 1, wc = wid & 1;

  const int bid = blockIdx.x;
  const int xcd = bid & 7;
  const int idx = bid >> 3;          // 0..191
  const int bx = xcd * 8 + (idx & 7);
  const int by = idx >> 3;           // 0..23
  const int m0 = bx * 128;
  const int sel = by >> 3;
  const int n0 = (by & 7) * 128;
  const unsigned short* Bm = (sel == 0) ? Wq : (sel == 1) ? Wk : Wv;
  unsigned short* outp = (sel == 0) ? Qo : (sel == 1) ? Ko : Vo;

  f32x4 acc[4][4] = {};

  for (int k0 = 0; k0 < K; k0 += 64) {
    __syncthreads();
#pragma unroll
    for (int pass = 0; pass < 4; ++pass) {
      int chunk = pass * 256 + tid;
      int row = chunk >> 3, inner = chunk & 7;
      const unsigned short* ga = A + (size_t)(m0 + row) * K + k0 + inner * 8;
      const unsigned short* gb = Bm + (size_t)(n0 + row) * K + k0 + inner * 8;
      unsigned short* la = Ab + (size_t)(pass * 256 + wid * 64) * 8;
      unsigned short* lb = Bb + (size_t)(pass * 256 + wid * 64) * 8;
      GLOAD_LDS16(ga, la);
      GLOAD_LDS16(gb, lb);
    }
    __syncthreads();
#pragma unroll
    for (int kk = 0; kk < 2; ++kk) {
      short8 af[4], bf[4];
#pragma unroll
      for (int mi = 0; mi < 4; ++mi)
        af[mi] = *(const short8*)&Ab[(wr * 64 + mi * 16 + lr) * 64 + kk * 32 + lk * 8];
#pragma unroll
      for (int ni = 0; ni < 4; ++ni)
        bf[ni] = *(const short8*)&Bb[(wc * 64 + ni * 16 + lr) * 64 + kk * 32 + lk * 8];
#pragma unroll
      for (int mi = 0; mi < 4; ++mi)
#pragma unroll
        for (int ni = 0; ni < 4; ++ni)
          acc[mi][ni] = MFMA_BF16(af[mi], bf[ni], acc[mi][ni]);
    }
  }

#pragma unroll
  for (int mi = 0; mi < 4; ++mi)
#pragma unroll
    for (int ni = 0; ni < 4; ++ni) {
      int row0 = m0 + wr * 64 + mi * 16 + lk * 4;
      int col = n0 + wc * 64 + ni * 16 + lr;
      int b = row0 >> 11, t0 = row0 & (T_ - 1), h = col >> 6, d = col & (D_ - 1);
      if (sel == 2) {
        short4v vv;
#pragma unroll
        for (int r = 0; r < 4; ++r) vv[r] = (short)f2bf(acc[mi][ni][r]);
        *(short4v*)&outp[(((size_t)(b * H_ + h)) * D_ + d) * T_ + t0] = vv;  // [BH][D][T]
      } else {
#pragma unroll
        for (int r = 0; r < 4; ++r)
          outp[(((size_t)(b * H_ + h)) * T_ + t0 + r) * D_ + d] = f2bf(acc[mi][ni][r]);
      }
    }
}

// ---------------- out-proj GEMM (XCD-swizzled 1D grid, 512 blocks) -----------
__global__ __launch_bounds__(256) void gemm_out(const unsigned short* __restrict__ A,
                                                const unsigned short* __restrict__ Bm,
                                                float* __restrict__ outp,
                                                const float* __restrict__ bias,
                                                int M, int N, int K) {
  __shared__ __align__(16) unsigned short Ab[128 * 64];
  __shared__ __align__(16) unsigned short Bb[128 * 64];
  const int tid = threadIdx.x;
  const int wid = tid >> 6;
  const int lr = tid & 15;
  const int lk = (tid >> 4) & 3;
  const int wr = wid >> 1, wc = wid & 1;

  const int bid = blockIdx.x;
  const int xcd = bid & 7;
  const int idx = bid >> 3;          // 0..63
  const int m0 = (xcd * 8 + (idx & 7)) * 128;
  const int n0 = (idx >> 3) * 128;

  f32x4 acc[4][4] = {};

  for (int k0 = 0; k0 < K; k0 += 64) {
    __syncthreads();
#pragma unroll
    for (int pass = 0; pass < 4; ++pass) {
      int chunk = pass * 256 + tid;
      int row = chunk >> 3, inner = chunk & 7;
      const unsigned short* ga = A + (size_t)(m0 + row) * K + k0 + inner * 8;
      const unsigned short* gb = Bm + (size_t)(n0 + row) * K + k0 + inner * 8;
      unsigned short* la = Ab + (size_t)(pass * 256 + wid * 64) * 8;
      unsigned short* lb = Bb + (size_t)(pass * 256 + wid * 64) * 8;
      GLOAD_LDS16(ga, la);
      GLOAD_LDS16(gb, lb);
    }
    __syncthreads();
#pragma unroll
    for (int kk = 0; kk < 2; ++kk) {
      short8 af[4], bf[4];
#pragma unroll
      for (int mi = 0; mi < 4; ++mi)
        af[mi] = *(const short8*)&Ab[(wr * 64 + mi * 16 + lr) * 64 + kk * 32 + lk * 8];
#pragma unroll
      for (int ni = 0; ni < 4; ++ni)
        bf[ni] = *(const short8*)&Bb[(wc * 64 + ni * 16 + lr) * 64 + kk * 32 + lk * 8];
#pragma unroll
      for (int mi = 0; mi < 4; ++mi)
#pragma unroll
        for (int ni = 0; ni < 4; ++ni)
          acc[mi][ni] = MFMA_BF16(af[mi], bf[ni], acc[mi][ni]);
    }
  }

#pragma unroll
  for (int mi = 0; mi < 4; ++mi)
#pragma unroll
    for (int ni = 0; ni < 4; ++ni)
#pragma unroll
      for (int r = 0; r < 4; ++r) {
        int row = m0 + wr * 64 + mi * 16 + lk * 4 + r;
        int col = n0 + wc * 64 + ni * 16 + lr;
        outp[(size_t)row * N + col] = acc[mi][ni][r] + bias[col];
      }
}

// ---------------- fused causal flash attention (r11 body + T5 setprio) -------
// 2048 blocks x 64 thr; wave owns 64 q-rows (chunks A,B) sharing K/V.
// Lagged-PV pipeline: iter i = {issue K(i+1),V(i); QK(i); rowmax(i);
// PV(i-1) from other P-buffer; rescale; pack(i)}. setprio(1) around MFMA
// clusters (independent 1-wave blocks at different phases per CU -> m191).
__global__ __launch_bounds__(64) void attn_fused(const unsigned short* __restrict__ Q,
                                                 const unsigned short* __restrict__ K,
                                                 const unsigned short* __restrict__ VT,
                                                 unsigned short* __restrict__ ctx) {
  __shared__ __align__(16) unsigned short Pl[2][64 * 72];  // 2 bufs x 64 rows x 144B
  const int lane = threadIdx.x & 63;
  const int lr = lane & 15;
  const int lk = lane >> 4;

  // XCD swizzle: 8 heads/XCD; heaviest 64-row groups dispatched first.
  const int bid = blockIdx.x;
  const int xcd = bid & 7;
  const int p = bid >> 3;       // 0..255 per XCD
  const int bh = xcd * 8 + (p & 7);
  const int c = 31 - (p >> 3);  // heavy first, 0..31
  const int q0 = c * 64;

  const unsigned short* Qh = Q + (size_t)bh * T_ * D_;
  const unsigned short* Kh = K + (size_t)bh * T_ * D_;
  const unsigned short* Vh = VT + (size_t)bh * T_ * D_;  // [D][T]
  char* bufA = (char*)&Pl[0][0];
  char* bufB = (char*)&Pl[1][0];

  const float SC = 0.125f * 1.44269504089f;  // 1/sqrt(D) * log2(e)

  short8 vones;
#pragma unroll
  for (int j = 0; j < 8; ++j) vones[j] = (short)0x3F80;  // bf16 1.0

  // Q as B-operand: col=q=lr, k=d
  short8 qfA[2][2], qfB[2][2];
#pragma unroll
  for (int a = 0; a < 2; ++a)
#pragma unroll
    for (int kb = 0; kb < 2; ++kb) {
      qfA[a][kb] = *(const short8*)&Qh[(size_t)(q0 + a * 16 + lr) * D_ + kb * 32 + lk * 8];
      qfB[a][kb] = *(const short8*)&Qh[(size_t)(q0 + 32 + a * 16 + lr) * D_ + kb * 32 + lk * 8];
    }

  f32x4 oA[2][4] = {}, oB[2][4] = {};
  f32x4 lsA[2] = {}, lsB[2] = {};
  float mA[2] = {-1e30f, -1e30f}, mB[2] = {-1e30f, -1e30f};

  const int nt = c + 1;

  auto loadK = [&](short8(&kf)[2][4], int t) {
    const unsigned short* Kt = Kh + (size_t)t * 64 * D_;
#pragma unroll
    for (int kb = 0; kb < 2; ++kb)
#pragma unroll
      for (int n = 0; n < 4; ++n)
        kf[kb][n] = *(const short8*)&Kt[(size_t)(n * 16 + lr) * D_ + kb * 32 + lk * 8];
  };
  auto loadV = [&](short8(&v)[2][4], int t) {
    const unsigned short* Vtt = Vh + (size_t)t * 64;
#pragma unroll
    for (int kb = 0; kb < 2; ++kb)
#pragma unroll
      for (int nd = 0; nd < 4; ++nd)
        v[kb][nd] = *(const short8*)&Vtt[(size_t)(nd * 16 + lr) * T_ + kb * 32 + lk * 8];
  };
  auto rowmax = [&](f32x4(&st)[2][4], float(&pm)[2]) {
#pragma unroll
    for (int a = 0; a < 2; ++a) {
      float m0 = fmaxf(fmaxf(st[a][0][0], st[a][1][0]), fmaxf(st[a][2][0], st[a][3][0]));
      float m1 = fmaxf(fmaxf(st[a][0][1], st[a][1][1]), fmaxf(st[a][2][1], st[a][3][1]));
      float m2 = fmaxf(fmaxf(st[a][0][2], st[a][1][2]), fmaxf(st[a][2][2], st[a][3][2]));
      float m3 = fmaxf(fmaxf(st[a][0][3], st[a][1][3]), fmaxf(st[a][2][3], st[a][3][3]));
      float mx = fmaxf(fmaxf(m0, m1), fmaxf(m2, m3));
      mx = fmaxf(mx, __shfl_xor(mx, 16));
      mx = fmaxf(mx, __shfl_xor(mx, 32));
      pm[a] = mx * SC;
    }
  };
  auto rescale1 = [&](float(&pm)[2], float(&mrun)[2], f32x4(&ls)[2], f32x4(&o)[2][4]) {
#pragma unroll
    for (int a = 0; a < 2; ++a) {
      float mnew = fmaxf(mrun[a], pm[a]);
      float sc = exp2f(mrun[a] - mnew);
      mrun[a] = mnew;
#pragma unroll
      for (int r = 0; r < 4; ++r) {
        float sco = __shfl(sc, (lane & 48) | (lk * 4 + r));
        ls[a][r] *= sco;
#pragma unroll
        for (int nd = 0; nd < 4; ++nd) o[a][nd][r] *= sco;
      }
    }
  };
  auto pack = [&](f32x4(&st)[2][4], float(&mrun)[2], char* buf, int rb) {
#pragma unroll
    for (int a = 0; a < 2; ++a)
#pragma unroll
      for (int n = 0; n < 4; ++n) {
        float2 p01, p23;
        p01.x = exp2f(fmaf(st[a][n][0], SC, -mrun[a]));
        p01.y = exp2f(fmaf(st[a][n][1], SC, -mrun[a]));
        p23.x = exp2f(fmaf(st[a][n][2], SC, -mrun[a]));
        p23.y = exp2f(fmaf(st[a][n][3], SC, -mrun[a]));
        __hip_bfloat162 b01 = __float22bfloat162_rn(p01);
        __hip_bfloat162 b23 = __float22bfloat162_rn(p23);
        uint2 w;
        w.x = *(unsigned*)&b01;
        w.y = *(unsigned*)&b23;
        *(uint2*)(buf + (rb + a * 16 + lr) * 144 + n * 32 + lk * 8) = w;
      }
  };
  auto pv = [&](char* buf, short8(&v)[2][4]) {
    __builtin_amdgcn_s_setprio(1);
#pragma unroll
    for (int kb = 0; kb < 2; ++kb) {
      short8 pfA0 = *(const short8*)(buf + (0 + lr) * 144 + kb * 64 + lk * 16);
      short8 pfA1 = *(const short8*)(buf + (16 + lr) * 144 + kb * 64 + lk * 16);
      short8 pfB0 = *(const short8*)(buf + (32 + lr) * 144 + kb * 64 + lk * 16);
      short8 pfB1 = *(const short8*)(buf + (48 + lr) * 144 + kb * 64 + lk * 16);
#pragma unroll
      for (int nd = 0; nd < 4; ++nd) {
        oA[0][nd] = MFMA_BF16(pfA0, v[kb][nd], oA[0][nd]);
        oA[1][nd] = MFMA_BF16(pfA1, v[kb][nd], oA[1][nd]);
        oB[0][nd] = MFMA_BF16(pfB0, v[kb][nd], oB[0][nd]);
        oB[1][nd] = MFMA_BF16(pfB1, v[kb][nd], oB[1][nd]);
      }
      lsA[0] = MFMA_BF16(pfA0, vones, lsA[0]);
      lsA[1] = MFMA_BF16(pfA1, vones, lsA[1]);
      lsB[0] = MFMA_BF16(pfB0, vones, lsB[0]);
      lsB[1] = MFMA_BF16(pfB1, vones, lsB[1]);
    }
    __builtin_amdgcn_s_setprio(0);
  };

  // per-tile body: QK(i) + rowmax + [PV(i-1)] + rescale + pack(i)
  auto tile = [&](int i, bool diag, bool doPV,
                  short8(&kfc)[2][4], short8(&kfn)[2][4],
                  short8(&vp)[2][4], short8(&vc)[2][4],
                  char* bufp, char* bufc, int tnext) {
    loadK(kfn, tnext);
    loadV(vc, i);
    f32x4 stA[2][4] = {}, stB[2][4] = {};
    __builtin_amdgcn_s_setprio(1);
#pragma unroll
    for (int kb = 0; kb < 2; ++kb)
#pragma unroll
      for (int a = 0; a < 2; ++a)
#pragma unroll
        for (int n = 0; n < 4; ++n) {
          stA[a][n] = MFMA_BF16(kfc[kb][n], qfA[a][kb], stA[a][n]);
          stB[a][n] = MFMA_BF16(kfc[kb][n], qfB[a][kb], stB[a][n]);
        }
    __builtin_amdgcn_s_setprio(0);
    if (diag) {
#pragma unroll
      for (int a = 0; a < 2; ++a)
#pragma unroll
        for (int n = 0; n < 4; ++n)
#pragma unroll
          for (int r = 0; r < 4; ++r) {
            if (n * 16 + lk * 4 + r > 0 + a * 16 + lr) stA[a][n][r] = -3e38f;
            if (n * 16 + lk * 4 + r > 32 + a * 16 + lr) stB[a][n][r] = -3e38f;
          }
    }
    float pmA[2], pmB[2];
    rowmax(stA, pmA);
    rowmax(stB, pmB);
    float need = fmaxf(fmaxf(pmA[0] - mA[0], pmA[1] - mA[1]),
                       fmaxf(pmB[0] - mB[0], pmB[1] - mB[1]));
    if (doPV) pv(bufp, vp);  // absorbs tile i-1 at OLD scale (before rescale)
    if (__any(need > 8.f)) {
      rescale1(pmA, mA, lsA, oA);
      rescale1(pmB, mB, lsB, oB);
    }
    pack(stA, mA, bufc, 0);
    pack(stB, mB, bufc, 32);
  };

  short8 kf0[2][4], kf1[2][4], v0[2][4], v1[2][4];

  // prologue: tile 0 (no PV), K(1) prefetched
  loadK(kf0, 0);
  tile(0, nt == 1, false, kf0, kf1, v1, v0, bufB, bufA, (1 < nt) ? 1 : 0);

  int i = 1;
  while (i < nt) {
    tile(i, i == nt - 1, true, kf1, kf0, v0, v1, bufA, bufB, (i + 1 < nt) ? i + 1 : i);
    if (++i >= nt) break;
    tile(i, i == nt - 1, true, kf0, kf1, v1, v0, bufB, bufA, (i + 1 < nt) ? i + 1 : i);
    ++i;
  }
  // epilogue: PV of last tile
  if ((nt - 1) & 1) pv(bufB, v1);
  else              pv(bufA, v0);

  const int b = bh >> 4, h2 = bh & 15;
#pragma unroll
  for (int a = 0; a < 2; ++a)
#pragma unroll
    for (int r = 0; r < 4; ++r) {
      float invA = 1.0f / lsA[a][r];
      float invB = 1.0f / lsB[a][r];
      int tA = q0 + a * 16 + lk * 4 + r;
      int tB = tA + 32;
#pragma unroll
      for (int nd = 0; nd < 4; ++nd) {
        ctx[((size_t)b * T_ + tA) * E_ + h2 * D_ + nd * 16 + lr] = f2bf(oA[a][nd][r] * invA);
        ctx[((size_t)b * T_ + tB) * E_ + h2 * D_ + nd * 16 + lr] = f2bf(oB[a][nd][r] * invB);
      }
    }
}

// ---------------- launcher ----------------
extern "C" void kernel_launch(void* const* d_in, const int* in_sizes, int n_in,
                              void* d_out, int out_size, void* d_ws, size_t ws_size,
                              hipStream_t stream) {
  const float* x    = (const float*)d_in[0];
  const float* Wq   = (const float*)d_in[1];
  const float* Wk   = (const float*)d_in[2];
  const float* Wv   = (const float*)d_in[3];
  const float* Wout = (const float*)d_in[4];
  const float* bout = (const float*)d_in[5];
  float* out = (float*)d_out;

  const size_t MT = (size_t)B_ * T_;      // 8192
  const size_t XE = MT * E_;              // 8,388,608
  const size_t WE = (size_t)E_ * E_;      // 1,048,576

  size_t need = (XE * 5 + WE * 4) * sizeof(unsigned short);
  if (ws_size < need) return;

  unsigned short* xb  = (unsigned short*)d_ws;
  unsigned short* wqb = xb + XE;
  unsigned short* wkb = wqb + WE;
  unsigned short* wvb = wkb + WE;
  unsigned short* wob = wvb + WE;
  unsigned short* Qb  = wob + WE;
  unsigned short* Kb  = Qb + XE;
  unsigned short* VTb = Kb + XE;
  unsigned short* ctx = VTb + XE;

  // (XE/8 + 4*WE/8) / 256 = (1048576 + 524288) / 256 = 6144 blocks
  cvt_all<<<6144, 256, 0, stream>>>(x, Wq, Wk, Wv, Wout, xb, wqb);

  gemm_qkv<<<1536, 256, 0, stream>>>(xb, wqb, wkb, wvb, Qb, Kb, VTb);  // V written transposed

  attn_fused<<<2048, 64, 0, stream>>>(Qb, Kb, VTb, ctx);

  gemm_out<<<512, 256, 0, stream>>>(ctx, wob, out, bout, (int)MT, E_, E_);
}

// Round 16
// 203.864 us; speedup vs baseline: 1.2696x; 1.2696x over previous
//
#include <hip/hip_runtime.h>
#include <hip/hip_bf16.h>
#include <stdint.h>
#include <math.h>

#define B_ 4
#define T_ 2048
#define E_ 1024
#define H_ 16
#define D_ 64

typedef __attribute__((ext_vector_type(8))) short short8;
typedef __attribute__((ext_vector_type(4))) short short4v;
typedef __attribute__((ext_vector_type(4))) float f32x4;

#define MFMA_BF16(a, b, c) __builtin_amdgcn_mfma_f32_16x16x32_bf16((a), (b), (c), 0, 0, 0)

__device__ __forceinline__ unsigned short f2bf(float f) {
  union { float f; unsigned u; } v; v.f = f;
  unsigned r = v.u + 0x7FFFu + ((v.u >> 16) & 1u);  // RNE
  return (unsigned short)(r >> 16);
}

#define GLOAD_LDS16(g, l)                                                        \
  __builtin_amdgcn_global_load_lds((const __attribute__((address_space(1))) void*)(g), \
                                   (__attribute__((address_space(3))) void*)(l), 16, 0, 0)

// ---------------- fp32 -> bf16 convert: x + 4 weights in ONE launch ----------
__global__ __launch_bounds__(256) void cvt_all(const float* __restrict__ x,
                                               const float* __restrict__ w0,
                                               const float* __restrict__ w1,
                                               const float* __restrict__ w2,
                                               const float* __restrict__ w3,
                                               unsigned short* __restrict__ xb,
                                               unsigned short* __restrict__ wb) {
  const int NX8 = 1048576;  // XE/8
  int i = blockIdx.x * blockDim.x + threadIdx.x;
  const float* src;
  unsigned short* dst;
  size_t off;
  if (i < NX8) {
    src = x; dst = xb; off = (size_t)i * 8;
  } else {
    int j = i - NX8;                 // 0 .. 4*WE/8-1
    int which = j >> 17;             // WE/8 = 2^17
    int o = j & 131071;
    src = (which == 0) ? w0 : (which == 1) ? w1 : (which == 2) ? w2 : w3;
    dst = wb + ((size_t)which << 20);
    off = (size_t)o * 8;
  }
  const float4* p = (const float4*)(src + off);
  float4 a = p[0], b = p[1];
  short8 r;
  r[0] = (short)f2bf(a.x); r[1] = (short)f2bf(a.y);
  r[2] = (short)f2bf(a.z); r[3] = (short)f2bf(a.w);
  r[4] = (short)f2bf(b.x); r[5] = (short)f2bf(b.y);
  r[6] = (short)f2bf(b.z); r[7] = (short)f2bf(b.w);
  *(short8*)(dst + off) = r;
}

// ---------------- fused QKV GEMM (XCD-swizzled 1D grid, 1536 blocks) ---------
// sel 0/1 (Q,K): bf16 [B*H][T][D]. sel 2 (V): bf16 TRANSPOSED [B*H][D][T].
__global__ __launch_bounds__(256) void gemm_qkv(const unsigned short* __restrict__ A,
                                                const unsigned short* __restrict__ Wq,
                                                const unsigned short* __restrict__ Wk,
                                                const unsigned short* __restrict__ Wv,
                                                unsigned short* __restrict__ Qo,
                                                unsigned short* __restrict__ Ko,
                                                unsigned short* __restrict__ Vo) {
  __shared__ __align__(16) unsigned short Ab[128 * 64];
  __shared__ __align__(16) unsigned short Bb[128 * 64];
  const int K = E_;
  const int tid = threadIdx.x;
  const int wid = tid >> 6;
  const int lr = tid & 15;
  const int lk = (tid >> 4) & 3;
  const int wr = wid >> 1, wc = wid & 1;

  const int bid = blockIdx.x;
  const int xcd = bid & 7;
  const int idx = bid >> 3;          // 0..191
  const int bx = xcd * 8 + (idx & 7);
  const int by = idx >> 3;           // 0..23
  const int m0 = bx * 128;
  const int sel = by >> 3;
  const int n0 = (by & 7) * 128;
  const unsigned short* Bm = (sel == 0) ? Wq : (sel == 1) ? Wk : Wv;
  unsigned short* outp = (sel == 0) ? Qo : (sel == 1) ? Ko : Vo;

  f32x4 acc[4][4] = {};

  for (int k0 = 0; k0 < K; k0 += 64) {
    __syncthreads();
#pragma unroll
    for (int pass = 0; pass < 4; ++pass) {
      int chunk = pass * 256 + tid;
      int row = chunk >> 3, inner = chunk & 7;
      const unsigned short* ga = A + (size_t)(m0 + row) * K + k0 + inner * 8;
      const unsigned short* gb = Bm + (size_t)(n0 + row) * K + k0 + inner * 8;
      unsigned short* la = Ab + (size_t)(pass * 256 + wid * 64) * 8;
      unsigned short* lb = Bb + (size_t)(pass * 256 + wid * 64) * 8;
      GLOAD_LDS16(ga, la);
      GLOAD_LDS16(gb, lb);
    }
    __syncthreads();
#pragma unroll
    for (int kk = 0; kk < 2; ++kk) {
      short8 af[4], bf[4];
#pragma unroll
      for (int mi = 0; mi < 4; ++mi)
        af[mi] = *(const short8*)&Ab[(wr * 64 + mi * 16 + lr) * 64 + kk * 32 + lk * 8];
#pragma unroll
      for (int ni = 0; ni < 4; ++ni)
        bf[ni] = *(const short8*)&Bb[(wc * 64 + ni * 16 + lr) * 64 + kk * 32 + lk * 8];
#pragma unroll
      for (int mi = 0; mi < 4; ++mi)
#pragma unroll
        for (int ni = 0; ni < 4; ++ni)
          acc[mi][ni] = MFMA_BF16(af[mi], bf[ni], acc[mi][ni]);
    }
  }

#pragma unroll
  for (int mi = 0; mi < 4; ++mi)
#pragma unroll
    for (int ni = 0; ni < 4; ++ni) {
      int row0 = m0 + wr * 64 + mi * 16 + lk * 4;
      int col = n0 + wc * 64 + ni * 16 + lr;
      int b = row0 >> 11, t0 = row0 & (T_ - 1), h = col >> 6, d = col & (D_ - 1);
      if (sel == 2) {
        short4v vv;
#pragma unroll
        for (int r = 0; r < 4; ++r) vv[r] = (short)f2bf(acc[mi][ni][r]);
        *(short4v*)&outp[(((size_t)(b * H_ + h)) * D_ + d) * T_ + t0] = vv;  // [BH][D][T]
      } else {
#pragma unroll
        for (int r = 0; r < 4; ++r)
          outp[(((size_t)(b * H_ + h)) * T_ + t0 + r) * D_ + d] = f2bf(acc[mi][ni][r]);
      }
    }
}

// ---------------- out-proj GEMM (XCD-swizzled 1D grid, 512 blocks) -----------
__global__ __launch_bounds__(256) void gemm_out(const unsigned short* __restrict__ A,
                                                const unsigned short* __restrict__ Bm,
                                                float* __restrict__ outp,
                                                const float* __restrict__ bias,
                                                int M, int N, int K) {
  __shared__ __align__(16) unsigned short Ab[128 * 64];
  __shared__ __align__(16) unsigned short Bb[128 * 64];
  const int tid = threadIdx.x;
  const int wid = tid >> 6;
  const int lr = tid & 15;
  const int lk = (tid >> 4) & 3;
  const int wr = wid >> 1, wc = wid & 1;

  const int bid = blockIdx.x;
  const int xcd = bid & 7;
  const int idx = bid >> 3;          // 0..63
  const int m0 = (xcd * 8 + (idx & 7)) * 128;
  const int n0 = (idx >> 3) * 128;

  f32x4 acc[4][4] = {};

  for (int k0 = 0; k0 < K; k0 += 64) {
    __syncthreads();
#pragma unroll
    for (int pass = 0; pass < 4; ++pass) {
      int chunk = pass * 256 + tid;
      int row = chunk >> 3, inner = chunk & 7;
      const unsigned short* ga = A + (size_t)(m0 + row) * K + k0 + inner * 8;
      const unsigned short* gb = Bm + (size_t)(n0 + row) * K + k0 + inner * 8;
      unsigned short* la = Ab + (size_t)(pass * 256 + wid * 64) * 8;
      unsigned short* lb = Bb + (size_t)(pass * 256 + wid * 64) * 8;
      GLOAD_LDS16(ga, la);
      GLOAD_LDS16(gb, lb);
    }
    __syncthreads();
#pragma unroll
    for (int kk = 0; kk < 2; ++kk) {
      short8 af[4], bf[4];
#pragma unroll
      for (int mi = 0; mi < 4; ++mi)
        af[mi] = *(const short8*)&Ab[(wr * 64 + mi * 16 + lr) * 64 + kk * 32 + lk * 8];
#pragma unroll
      for (int ni = 0; ni < 4; ++ni)
        bf[ni] = *(const short8*)&Bb[(wc * 64 + ni * 16 + lr) * 64 + kk * 32 + lk * 8];
#pragma unroll
      for (int mi = 0; mi < 4; ++mi)
#pragma unroll
        for (int ni = 0; ni < 4; ++ni)
          acc[mi][ni] = MFMA_BF16(af[mi], bf[ni], acc[mi][ni]);
    }
  }

#pragma unroll
  for (int mi = 0; mi < 4; ++mi)
#pragma unroll
    for (int ni = 0; ni < 4; ++ni)
#pragma unroll
      for (int r = 0; r < 4; ++r) {
        int row = m0 + wr * 64 + mi * 16 + lk * 4 + r;
        int col = n0 + wc * 64 + ni * 16 + lr;
        outp[(size_t)row * N + col] = acc[mi][ni][r] + bias[col];
      }
}

// ---------------- fused causal flash attention (r11 body, verbatim) ----------
// 2048 blocks x 64 thr; wave owns 64 q-rows (chunks A,B) sharing K/V.
// Lagged-PV pipeline: iter i = {issue K(i+1),V(i); QK(i); rowmax(i);
// PV(i-1) from other P-buffer; rescale; pack(i)}. NO setprio (r15: at 244
// VGPR any scheduling-point insertion spills — VGPR 256 + 40MB scratch).
__global__ __launch_bounds__(64) void attn_fused(const unsigned short* __restrict__ Q,
                                                 const unsigned short* __restrict__ K,
                                                 const unsigned short* __restrict__ VT,
                                                 unsigned short* __restrict__ ctx) {
  __shared__ __align__(16) unsigned short Pl[2][64 * 72];  // 2 bufs x 64 rows x 144B
  const int lane = threadIdx.x & 63;
  const int lr = lane & 15;
  const int lk = lane >> 4;

  // XCD swizzle: 8 heads/XCD; heaviest 64-row groups dispatched first.
  const int bid = blockIdx.x;
  const int xcd = bid & 7;
  const int p = bid >> 3;       // 0..255 per XCD
  const int bh = xcd * 8 + (p & 7);
  const int c = 31 - (p >> 3);  // heavy first, 0..31
  const int q0 = c * 64;

  const unsigned short* Qh = Q + (size_t)bh * T_ * D_;
  const unsigned short* Kh = K + (size_t)bh * T_ * D_;
  const unsigned short* Vh = VT + (size_t)bh * T_ * D_;  // [D][T]
  char* bufA = (char*)&Pl[0][0];
  char* bufB = (char*)&Pl[1][0];

  const float SC = 0.125f * 1.44269504089f;  // 1/sqrt(D) * log2(e)

  short8 vones;
#pragma unroll
  for (int j = 0; j < 8; ++j) vones[j] = (short)0x3F80;  // bf16 1.0

  // Q as B-operand: col=q=lr, k=d
  short8 qfA[2][2], qfB[2][2];
#pragma unroll
  for (int a = 0; a < 2; ++a)
#pragma unroll
    for (int kb = 0; kb < 2; ++kb) {
      qfA[a][kb] = *(const short8*)&Qh[(size_t)(q0 + a * 16 + lr) * D_ + kb * 32 + lk * 8];
      qfB[a][kb] = *(const short8*)&Qh[(size_t)(q0 + 32 + a * 16 + lr) * D_ + kb * 32 + lk * 8];
    }

  f32x4 oA[2][4] = {}, oB[2][4] = {};
  f32x4 lsA[2] = {}, lsB[2] = {};
  float mA[2] = {-1e30f, -1e30f}, mB[2] = {-1e30f, -1e30f};

  const int nt = c + 1;

  auto loadK = [&](short8(&kf)[2][4], int t) {
    const unsigned short* Kt = Kh + (size_t)t * 64 * D_;
#pragma unroll
    for (int kb = 0; kb < 2; ++kb)
#pragma unroll
      for (int n = 0; n < 4; ++n)
        kf[kb][n] = *(const short8*)&Kt[(size_t)(n * 16 + lr) * D_ + kb * 32 + lk * 8];
  };
  auto loadV = [&](short8(&v)[2][4], int t) {
    const unsigned short* Vtt = Vh + (size_t)t * 64;
#pragma unroll
    for (int kb = 0; kb < 2; ++kb)
#pragma unroll
      for (int nd = 0; nd < 4; ++nd)
        v[kb][nd] = *(const short8*)&Vtt[(size_t)(nd * 16 + lr) * T_ + kb * 32 + lk * 8];
  };
  auto rowmax = [&](f32x4(&st)[2][4], float(&pm)[2]) {
#pragma unroll
    for (int a = 0; a < 2; ++a) {
      float m0 = fmaxf(fmaxf(st[a][0][0], st[a][1][0]), fmaxf(st[a][2][0], st[a][3][0]));
      float m1 = fmaxf(fmaxf(st[a][0][1], st[a][1][1]), fmaxf(st[a][2][1], st[a][3][1]));
      float m2 = fmaxf(fmaxf(st[a][0][2], st[a][1][2]), fmaxf(st[a][2][2], st[a][3][2]));
      float m3 = fmaxf(fmaxf(st[a][0][3], st[a][1][3]), fmaxf(st[a][2][3], st[a][3][3]));
      float mx = fmaxf(fmaxf(m0, m1), fmaxf(m2, m3));
      mx = fmaxf(mx, __shfl_xor(mx, 16));
      mx = fmaxf(mx, __shfl_xor(mx, 32));
      pm[a] = mx * SC;
    }
  };
  auto rescale1 = [&](float(&pm)[2], float(&mrun)[2], f32x4(&ls)[2], f32x4(&o)[2][4]) {
#pragma unroll
    for (int a = 0; a < 2; ++a) {
      float mnew = fmaxf(mrun[a], pm[a]);
      float sc = exp2f(mrun[a] - mnew);
      mrun[a] = mnew;
#pragma unroll
      for (int r = 0; r < 4; ++r) {
        float sco = __shfl(sc, (lane & 48) | (lk * 4 + r));
        ls[a][r] *= sco;
#pragma unroll
        for (int nd = 0; nd < 4; ++nd) o[a][nd][r] *= sco;
      }
    }
  };
  auto pack = [&](f32x4(&st)[2][4], float(&mrun)[2], char* buf, int rb) {
#pragma unroll
    for (int a = 0; a < 2; ++a)
#pragma unroll
      for (int n = 0; n < 4; ++n) {
        float2 p01, p23;
        p01.x = exp2f(fmaf(st[a][n][0], SC, -mrun[a]));
        p01.y = exp2f(fmaf(st[a][n][1], SC, -mrun[a]));
        p23.x = exp2f(fmaf(st[a][n][2], SC, -mrun[a]));
        p23.y = exp2f(fmaf(st[a][n][3], SC, -mrun[a]));
        __hip_bfloat162 b01 = __float22bfloat162_rn(p01);
        __hip_bfloat162 b23 = __float22bfloat162_rn(p23);
        uint2 w;
        w.x = *(unsigned*)&b01;
        w.y = *(unsigned*)&b23;
        *(uint2*)(buf + (rb + a * 16 + lr) * 144 + n * 32 + lk * 8) = w;
      }
  };
  auto pv = [&](char* buf, short8(&v)[2][4]) {
#pragma unroll
    for (int kb = 0; kb < 2; ++kb) {
      short8 pfA0 = *(const short8*)(buf + (0 + lr) * 144 + kb * 64 + lk * 16);
      short8 pfA1 = *(const short8*)(buf + (16 + lr) * 144 + kb * 64 + lk * 16);
      short8 pfB0 = *(const short8*)(buf + (32 + lr) * 144 + kb * 64 + lk * 16);
      short8 pfB1 = *(const short8*)(buf + (48 + lr) * 144 + kb * 64 + lk * 16);
#pragma unroll
      for (int nd = 0; nd < 4; ++nd) {
        oA[0][nd] = MFMA_BF16(pfA0, v[kb][nd], oA[0][nd]);
        oA[1][nd] = MFMA_BF16(pfA1, v[kb][nd], oA[1][nd]);
        oB[0][nd] = MFMA_BF16(pfB0, v[kb][nd], oB[0][nd]);
        oB[1][nd] = MFMA_BF16(pfB1, v[kb][nd], oB[1][nd]);
      }
      lsA[0] = MFMA_BF16(pfA0, vones, lsA[0]);
      lsA[1] = MFMA_BF16(pfA1, vones, lsA[1]);
      lsB[0] = MFMA_BF16(pfB0, vones, lsB[0]);
      lsB[1] = MFMA_BF16(pfB1, vones, lsB[1]);
    }
  };

  // per-tile body: QK(i) + rowmax + [PV(i-1)] + rescale + pack(i)
  auto tile = [&](int i, bool diag, bool doPV,
                  short8(&kfc)[2][4], short8(&kfn)[2][4],
                  short8(&vp)[2][4], short8(&vc)[2][4],
                  char* bufp, char* bufc, int tnext) {
    loadK(kfn, tnext);
    loadV(vc, i);
    f32x4 stA[2][4] = {}, stB[2][4] = {};
#pragma unroll
    for (int kb = 0; kb < 2; ++kb)
#pragma unroll
      for (int a = 0; a < 2; ++a)
#pragma unroll
        for (int n = 0; n < 4; ++n) {
          stA[a][n] = MFMA_BF16(kfc[kb][n], qfA[a][kb], stA[a][n]);
          stB[a][n] = MFMA_BF16(kfc[kb][n], qfB[a][kb], stB[a][n]);
        }
    if (diag) {
#pragma unroll
      for (int a = 0; a < 2; ++a)
#pragma unroll
        for (int n = 0; n < 4; ++n)
#pragma unroll
          for (int r = 0; r < 4; ++r) {
            if (n * 16 + lk * 4 + r > 0 + a * 16 + lr) stA[a][n][r] = -3e38f;
            if (n * 16 + lk * 4 + r > 32 + a * 16 + lr) stB[a][n][r] = -3e38f;
          }
    }
    float pmA[2], pmB[2];
    rowmax(stA, pmA);
    rowmax(stB, pmB);
    float need = fmaxf(fmaxf(pmA[0] - mA[0], pmA[1] - mA[1]),
                       fmaxf(pmB[0] - mB[0], pmB[1] - mB[1]));
    if (doPV) pv(bufp, vp);  // absorbs tile i-1 at OLD scale (before rescale)
    if (__any(need > 8.f)) {
      rescale1(pmA, mA, lsA, oA);
      rescale1(pmB, mB, lsB, oB);
    }
    pack(stA, mA, bufc, 0);
    pack(stB, mB, bufc, 32);
  };

  short8 kf0[2][4], kf1[2][4], v0[2][4], v1[2][4];

  // prologue: tile 0 (no PV), K(1) prefetched
  loadK(kf0, 0);
  tile(0, nt == 1, false, kf0, kf1, v1, v0, bufB, bufA, (1 < nt) ? 1 : 0);

  int i = 1;
  while (i < nt) {
    tile(i, i == nt - 1, true, kf1, kf0, v0, v1, bufA, bufB, (i + 1 < nt) ? i + 1 : i);
    if (++i >= nt) break;
    tile(i, i == nt - 1, true, kf0, kf1, v1, v0, bufB, bufA, (i + 1 < nt) ? i + 1 : i);
    ++i;
  }
  // epilogue: PV of last tile
  if ((nt - 1) & 1) pv(bufB, v1);
  else              pv(bufA, v0);

  const int b = bh >> 4, h2 = bh & 15;
#pragma unroll
  for (int a = 0; a < 2; ++a)
#pragma unroll
    for (int r = 0; r < 4; ++r) {
      float invA = 1.0f / lsA[a][r];
      float invB = 1.0f / lsB[a][r];
      int tA = q0 + a * 16 + lk * 4 + r;
      int tB = tA + 32;
#pragma unroll
      for (int nd = 0; nd < 4; ++nd) {
        ctx[((size_t)b * T_ + tA) * E_ + h2 * D_ + nd * 16 + lr] = f2bf(oA[a][nd][r] * invA);
        ctx[((size_t)b * T_ + tB) * E_ + h2 * D_ + nd * 16 + lr] = f2bf(oB[a][nd][r] * invB);
      }
    }
}

// ---------------- launcher ----------------
extern "C" void kernel_launch(void* const* d_in, const int* in_sizes, int n_in,
                              void* d_out, int out_size, void* d_ws, size_t ws_size,
                              hipStream_t stream) {
  const float* x    = (const float*)d_in[0];
  const float* Wq   = (const float*)d_in[1];
  const float* Wk   = (const float*)d_in[2];
  const float* Wv   = (const float*)d_in[3];
  const float* Wout = (const float*)d_in[4];
  const float* bout = (const float*)d_in[5];
  float* out = (float*)d_out;

  const size_t MT = (size_t)B_ * T_;      // 8192
  const size_t XE = MT * E_;              // 8,388,608
  const size_t WE = (size_t)E_ * E_;      // 1,048,576

  size_t need = (XE * 5 + WE * 4) * sizeof(unsigned short);
  if (ws_size < need) return;

  unsigned short* xb  = (unsigned short*)d_ws;
  unsigned short* wqb = xb + XE;
  unsigned short* wkb = wqb + WE;
  unsigned short* wvb = wkb + WE;
  unsigned short* wob = wvb + WE;
  unsigned short* Qb  = wob + WE;
  unsigned short* Kb  = Qb + XE;
  unsigned short* VTb = Kb + XE;
  unsigned short* ctx = VTb + XE;

  // (XE/8 + 4*WE/8) / 256 = 6144 blocks
  cvt_all<<<6144, 256, 0, stream>>>(x, Wq, Wk, Wv, Wout, xb, wqb);

  gemm_qkv<<<1536, 256, 0, stream>>>(xb, wqb, wkb, wvb, Qb, Kb, VTb);  // V written transposed

  attn_fused<<<2048, 64, 0, stream>>>(Qb, Kb, VTb, ctx);

  gemm_out<<<512, 256, 0, stream>>>(ctx, wob, out, bout, (int)MT, E_, E_);
}

// Round 17
// 194.519 us; speedup vs baseline: 1.3306x; 1.0480x over previous
//
#include <hip/hip_runtime.h>
#include <hip/hip_bf16.h>
#include <stdint.h>
#include <math.h>

#define B_ 4
#define T_ 2048
#define E_ 1024
#define H_ 16
#define D_ 64

typedef __attribute__((ext_vector_type(8))) short short8;
typedef __attribute__((ext_vector_type(4))) short short4v;
typedef __attribute__((ext_vector_type(4))) float f32x4;

#define MFMA_BF16(a, b, c) __builtin_amdgcn_mfma_f32_16x16x32_bf16((a), (b), (c), 0, 0, 0)

__device__ __forceinline__ unsigned short f2bf(float f) {
  union { float f; unsigned u; } v; v.f = f;
  unsigned r = v.u + 0x7FFFu + ((v.u >> 16) & 1u);  // RNE
  return (unsigned short)(r >> 16);
}

#define GLOAD_LDS16(g, l)                                                        \
  __builtin_amdgcn_global_load_lds((const __attribute__((address_space(1))) void*)(g), \
                                   (__attribute__((address_space(3))) void*)(l), 16, 0, 0)

// ---------------- fp32 -> bf16 convert: x + 4 weights in ONE launch ----------
__global__ __launch_bounds__(256) void cvt_all(const float* __restrict__ x,
                                               const float* __restrict__ w0,
                                               const float* __restrict__ w1,
                                               const float* __restrict__ w2,
                                               const float* __restrict__ w3,
                                               unsigned short* __restrict__ xb,
                                               unsigned short* __restrict__ wb) {
  const int NX8 = 1048576;  // XE/8
  int i = blockIdx.x * blockDim.x + threadIdx.x;
  const float* src;
  unsigned short* dst;
  size_t off;
  if (i < NX8) {
    src = x; dst = xb; off = (size_t)i * 8;
  } else {
    int j = i - NX8;
    int which = j >> 17;             // WE/8 = 2^17
    int o = j & 131071;
    src = (which == 0) ? w0 : (which == 1) ? w1 : (which == 2) ? w2 : w3;
    dst = wb + ((size_t)which << 20);
    off = (size_t)o * 8;
  }
  const float4* p = (const float4*)(src + off);
  float4 a = p[0], b = p[1];
  short8 r;
  r[0] = (short)f2bf(a.x); r[1] = (short)f2bf(a.y);
  r[2] = (short)f2bf(a.z); r[3] = (short)f2bf(a.w);
  r[4] = (short)f2bf(b.x); r[5] = (short)f2bf(b.y);
  r[6] = (short)f2bf(b.z); r[7] = (short)f2bf(b.w);
  *(short8*)(dst + off) = r;
}

// ---------------- 8-phase 256x256 QKV GEMM (m201 template port) --------------
// C = x * W^T for W in {Wq,Wk,Wv}. 384 blocks x 512 thr (8 waves, 2Mx4N).
// BK=64, double-buffered 128KB LDS, st_16x32 swizzle (pre-swizzled global
// source + swizzled ds_read), staging 2 K-tiles ahead, counted vmcnt(4).
// sel 0/1 (Q,K): bf16 [B*H][T][D]; sel 2 (V): bf16 transposed [B*H][D][T].
__global__ __launch_bounds__(512) void gemm_qkv8(const unsigned short* __restrict__ A,
                                                 const unsigned short* __restrict__ Wq,
                                                 const unsigned short* __restrict__ Wk,
                                                 const unsigned short* __restrict__ Wv,
                                                 unsigned short* __restrict__ Qo,
                                                 unsigned short* __restrict__ Ko,
                                                 unsigned short* __restrict__ Vo) {
  __shared__ __align__(16) char lds[131072];  // [2 buf][A 32K | B 32K]
  const int K = E_;
  const int NT = K / 64;  // 16
  const int tid = threadIdx.x;
  const int wid = tid >> 6;
  const int lane = tid & 63;
  const int lr = lane & 15;
  const int lk = lane >> 4;
  const int wm = wid >> 2;  // 0..1
  const int wn = wid & 3;   // 0..3

  const int bid = blockIdx.x;
  const int mp = bid & 31;
  const int rest = bid >> 5;   // 0..11
  const int np = rest & 3;
  const int sel = rest >> 2;   // 0..2
  const int m0 = mp * 256;
  const int n0 = np * 256;
  const unsigned short* Bm = (sel == 0) ? Wq : (sel == 1) ? Wk : Wv;

  // staging source lane constants (pre-swizzled global col)
  const int srow = lane >> 3;                              // 0..7
  const int scol = ((lane & 7) * 8) ^ ((lane & 32) ? 16 : 0);

  auto stageA = [&](int tau, int h) {
    char* dst = lds + (tau & 1) * 65536 + h * 16384 + wid * 1024;
    const unsigned short* src = A + (size_t)(m0 + h * 128 + wid * 8 + srow) * K + tau * 64 + scol;
    GLOAD_LDS16(src, dst);
    GLOAD_LDS16(src + (size_t)64 * K, dst + 8192);
  };
  auto stageB = [&](int tau, int h) {
    char* dst = lds + (tau & 1) * 65536 + 32768 + h * 16384 + wid * 1024;
    const unsigned short* src = Bm + (size_t)(n0 + h * 128 + wid * 8 + srow) * K + tau * 64 + scol;
    GLOAD_LDS16(src, dst);
    GLOAD_LDS16(src + (size_t)64 * K, dst + 8192);
  };

  // ds_read swizzle: byte col offset ^ 32 for lr&4
  const int swzr = (lr & 4) ? 32 : 0;
  const int kofs0 = (lk * 16) ^ swzr;        // kh=0
  const int kofs1 = (64 + lk * 16) ^ swzr;   // kh=1

  f32x4 acc[8][4] = {};
  short8 af[4][2], bf0[2][2], bf1[2][2];

  auto readA = [&](char* bufA, int miq) {
#pragma unroll
    for (int i = 0; i < 4; ++i) {
      int row = wm * 128 + (miq * 4 + i) * 16 + lr;
      af[i][0] = *(const short8*)(bufA + row * 128 + kofs0);
      af[i][1] = *(const short8*)(bufA + row * 128 + kofs1);
    }
  };
  auto readB = [&](short8(&bf)[2][2], char* bufB, int niq) {
#pragma unroll
    for (int i = 0; i < 2; ++i) {
      int row = wn * 64 + (niq * 2 + i) * 16 + lr;
      bf[i][0] = *(const short8*)(bufB + row * 128 + kofs0);
      bf[i][1] = *(const short8*)(bufB + row * 128 + kofs1);
    }
  };
  auto mfma_q = [&](short8(&b)[2][2], int mo, int no) {
#pragma unroll
    for (int i = 0; i < 4; ++i)
#pragma unroll
      for (int j = 0; j < 2; ++j) {
        acc[mo + i][no + j] = MFMA_BF16(af[i][0], b[j][0], acc[mo + i][no + j]);
        acc[mo + i][no + j] = MFMA_BF16(af[i][1], b[j][1], acc[mo + i][no + j]);
      }
  };

#define BAR() __builtin_amdgcn_s_barrier()
#define LGKM0() do { asm volatile("s_waitcnt lgkmcnt(0)" ::: "memory"); \
                     __builtin_amdgcn_sched_barrier(0); } while (0)

  // prologue: t0 all 4 halves + t1 B halves; wait t0 complete (4 newest ok)
  stageA(0, 0); stageA(0, 1); stageB(0, 0); stageB(0, 1);
  stageB(1, 0); stageB(1, 1);
  asm volatile("s_waitcnt vmcnt(4)" ::: "memory");
  BAR();

  for (int t = 0; t < NT; ++t) {
    char* bufA = lds + (t & 1) * 65536;
    char* bufB = bufA + 32768;
    // ph1: read A-lo + B-lo; stage A0(t+1); MFMA (m-lo, n-lo)
    readA(bufA, 0);
    readB(bf0, bufB, 0);
    if (t + 1 < NT) stageA(t + 1, 0);
    BAR(); LGKM0();
    __builtin_amdgcn_s_setprio(1);
    mfma_q(bf0, 0, 0);
    __builtin_amdgcn_s_setprio(0);
    BAR();
    // ph2: read B-hi; stage A1(t+1); MFMA (m-lo, n-hi)
    readB(bf1, bufB, 1);
    if (t + 1 < NT) stageA(t + 1, 1);
    BAR(); LGKM0();
    __builtin_amdgcn_s_setprio(1);
    mfma_q(bf1, 0, 2);
    __builtin_amdgcn_s_setprio(0);
    BAR();
    // ph3: read A-hi; stage B0(t+2); MFMA (m-hi, n-hi)
    readA(bufA, 1);
    if (t + 2 < NT) stageB(t + 2, 0);
    BAR(); LGKM0();
    __builtin_amdgcn_s_setprio(1);
    mfma_q(bf1, 4, 2);
    __builtin_amdgcn_s_setprio(0);
    BAR();
    // ph4: no reads; stage B1(t+2); MFMA (m-hi, n-lo); counted vmcnt
    if (t + 2 < NT) stageB(t + 2, 1);
    __builtin_amdgcn_s_setprio(1);
    mfma_q(bf0, 4, 0);
    __builtin_amdgcn_s_setprio(0);
    if (t < NT - 2) asm volatile("s_waitcnt vmcnt(4)" ::: "memory");
    else            asm volatile("s_waitcnt vmcnt(0)" ::: "memory");
    BAR();
  }
#undef BAR
#undef LGKM0

  // epilogue
  unsigned short* outp = (sel == 0) ? Qo : (sel == 1) ? Ko : Vo;
#pragma unroll
  for (int mi = 0; mi < 8; ++mi)
#pragma unroll
    for (int ni = 0; ni < 4; ++ni) {
      int row0 = m0 + wm * 128 + mi * 16 + lk * 4;
      int col = n0 + wn * 64 + ni * 16 + lr;
      int b = row0 >> 11, t0 = row0 & (T_ - 1), h = col >> 6, d = col & (D_ - 1);
      if (sel == 2) {
        short4v vv;
#pragma unroll
        for (int r = 0; r < 4; ++r) vv[r] = (short)f2bf(acc[mi][ni][r]);
        *(short4v*)&outp[(((size_t)(b * H_ + h)) * D_ + d) * T_ + t0] = vv;  // [BH][D][T]
      } else {
#pragma unroll
        for (int r = 0; r < 4; ++r)
          outp[(((size_t)(b * H_ + h)) * T_ + t0 + r) * D_ + d] = f2bf(acc[mi][ni][r]);
      }
    }
}

// ---------------- out-proj GEMM (unchanged r16) ----------------
__global__ __launch_bounds__(256) void gemm_out(const unsigned short* __restrict__ A,
                                                const unsigned short* __restrict__ Bm,
                                                float* __restrict__ outp,
                                                const float* __restrict__ bias,
                                                int M, int N, int K) {
  __shared__ __align__(16) unsigned short Ab[128 * 64];
  __shared__ __align__(16) unsigned short Bb[128 * 64];
  const int tid = threadIdx.x;
  const int wid = tid >> 6;
  const int lr = tid & 15;
  const int lk = (tid >> 4) & 3;
  const int wr = wid >> 1, wc = wid & 1;

  const int bid = blockIdx.x;
  const int xcd = bid & 7;
  const int idx = bid >> 3;
  const int m0 = (xcd * 8 + (idx & 7)) * 128;
  const int n0 = (idx >> 3) * 128;

  f32x4 acc[4][4] = {};

  for (int k0 = 0; k0 < K; k0 += 64) {
    __syncthreads();
#pragma unroll
    for (int pass = 0; pass < 4; ++pass) {
      int chunk = pass * 256 + tid;
      int row = chunk >> 3, inner = chunk & 7;
      const unsigned short* ga = A + (size_t)(m0 + row) * K + k0 + inner * 8;
      const unsigned short* gb = Bm + (size_t)(n0 + row) * K + k0 + inner * 8;
      unsigned short* la = Ab + (size_t)(pass * 256 + wid * 64) * 8;
      unsigned short* lb = Bb + (size_t)(pass * 256 + wid * 64) * 8;
      GLOAD_LDS16(ga, la);
      GLOAD_LDS16(gb, lb);
    }
    __syncthreads();
#pragma unroll
    for (int kk = 0; kk < 2; ++kk) {
      short8 af[4], bf[4];
#pragma unroll
      for (int mi = 0; mi < 4; ++mi)
        af[mi] = *(const short8*)&Ab[(wr * 64 + mi * 16 + lr) * 64 + kk * 32 + lk * 8];
#pragma unroll
      for (int ni = 0; ni < 4; ++ni)
        bf[ni] = *(const short8*)&Bb[(wc * 64 + ni * 16 + lr) * 64 + kk * 32 + lk * 8];
#pragma unroll
      for (int mi = 0; mi < 4; ++mi)
#pragma unroll
        for (int ni = 0; ni < 4; ++ni)
          acc[mi][ni] = MFMA_BF16(af[mi], bf[ni], acc[mi][ni]);
    }
  }

#pragma unroll
  for (int mi = 0; mi < 4; ++mi)
#pragma unroll
    for (int ni = 0; ni < 4; ++ni)
#pragma unroll
      for (int r = 0; r < 4; ++r) {
        int row = m0 + wr * 64 + mi * 16 + lk * 4 + r;
        int col = n0 + wc * 64 + ni * 16 + lr;
        outp[(size_t)row * N + col] = acc[mi][ni][r] + bias[col];
      }
}

// ---------------- fused causal flash attention (r11 body, verbatim) ----------
__global__ __launch_bounds__(64) void attn_fused(const unsigned short* __restrict__ Q,
                                                 const unsigned short* __restrict__ K,
                                                 const unsigned short* __restrict__ VT,
                                                 unsigned short* __restrict__ ctx) {
  __shared__ __align__(16) unsigned short Pl[2][64 * 72];
  const int lane = threadIdx.x & 63;
  const int lr = lane & 15;
  const int lk = lane >> 4;

  const int bid = blockIdx.x;
  const int xcd = bid & 7;
  const int p = bid >> 3;
  const int bh = xcd * 8 + (p & 7);
  const int c = 31 - (p >> 3);
  const int q0 = c * 64;

  const unsigned short* Qh = Q + (size_t)bh * T_ * D_;
  const unsigned short* Kh = K + (size_t)bh * T_ * D_;
  const unsigned short* Vh = VT + (size_t)bh * T_ * D_;
  char* bufA = (char*)&Pl[0][0];
  char* bufB = (char*)&Pl[1][0];

  const float SC = 0.125f * 1.44269504089f;

  short8 vones;
#pragma unroll
  for (int j = 0; j < 8; ++j) vones[j] = (short)0x3F80;

  short8 qfA[2][2], qfB[2][2];
#pragma unroll
  for (int a = 0; a < 2; ++a)
#pragma unroll
    for (int kb = 0; kb < 2; ++kb) {
      qfA[a][kb] = *(const short8*)&Qh[(size_t)(q0 + a * 16 + lr) * D_ + kb * 32 + lk * 8];
      qfB[a][kb] = *(const short8*)&Qh[(size_t)(q0 + 32 + a * 16 + lr) * D_ + kb * 32 + lk * 8];
    }

  f32x4 oA[2][4] = {}, oB[2][4] = {};
  f32x4 lsA[2] = {}, lsB[2] = {};
  float mA[2] = {-1e30f, -1e30f}, mB[2] = {-1e30f, -1e30f};

  const int nt = c + 1;

  auto loadK = [&](short8(&kf)[2][4], int t) {
    const unsigned short* Kt = Kh + (size_t)t * 64 * D_;
#pragma unroll
    for (int kb = 0; kb < 2; ++kb)
#pragma unroll
      for (int n = 0; n < 4; ++n)
        kf[kb][n] = *(const short8*)&Kt[(size_t)(n * 16 + lr) * D_ + kb * 32 + lk * 8];
  };
  auto loadV = [&](short8(&v)[2][4], int t) {
    const unsigned short* Vtt = Vh + (size_t)t * 64;
#pragma unroll
    for (int kb = 0; kb < 2; ++kb)
#pragma unroll
      for (int nd = 0; nd < 4; ++nd)
        v[kb][nd] = *(const short8*)&Vtt[(size_t)(nd * 16 + lr) * T_ + kb * 32 + lk * 8];
  };
  auto rowmax = [&](f32x4(&st)[2][4], float(&pm)[2]) {
#pragma unroll
    for (int a = 0; a < 2; ++a) {
      float m0 = fmaxf(fmaxf(st[a][0][0], st[a][1][0]), fmaxf(st[a][2][0], st[a][3][0]));
      float m1 = fmaxf(fmaxf(st[a][0][1], st[a][1][1]), fmaxf(st[a][2][1], st[a][3][1]));
      float m2 = fmaxf(fmaxf(st[a][0][2], st[a][1][2]), fmaxf(st[a][2][2], st[a][3][2]));
      float m3 = fmaxf(fmaxf(st[a][0][3], st[a][1][3]), fmaxf(st[a][2][3], st[a][3][3]));
      float mx = fmaxf(fmaxf(m0, m1), fmaxf(m2, m3));
      mx = fmaxf(mx, __shfl_xor(mx, 16));
      mx = fmaxf(mx, __shfl_xor(mx, 32));
      pm[a] = mx * SC;
    }
  };
  auto rescale1 = [&](float(&pm)[2], float(&mrun)[2], f32x4(&ls)[2], f32x4(&o)[2][4]) {
#pragma unroll
    for (int a = 0; a < 2; ++a) {
      float mnew = fmaxf(mrun[a], pm[a]);
      float sc = exp2f(mrun[a] - mnew);
      mrun[a] = mnew;
#pragma unroll
      for (int r = 0; r < 4; ++r) {
        float sco = __shfl(sc, (lane & 48) | (lk * 4 + r));
        ls[a][r] *= sco;
#pragma unroll
        for (int nd = 0; nd < 4; ++nd) o[a][nd][r] *= sco;
      }
    }
  };
  auto pack = [&](f32x4(&st)[2][4], float(&mrun)[2], char* buf, int rb) {
#pragma unroll
    for (int a = 0; a < 2; ++a)
#pragma unroll
      for (int n = 0; n < 4; ++n) {
        float2 p01, p23;
        p01.x = exp2f(fmaf(st[a][n][0], SC, -mrun[a]));
        p01.y = exp2f(fmaf(st[a][n][1], SC, -mrun[a]));
        p23.x = exp2f(fmaf(st[a][n][2], SC, -mrun[a]));
        p23.y = exp2f(fmaf(st[a][n][3], SC, -mrun[a]));
        __hip_bfloat162 b01 = __float22bfloat162_rn(p01);
        __hip_bfloat162 b23 = __float22bfloat162_rn(p23);
        uint2 w;
        w.x = *(unsigned*)&b01;
        w.y = *(unsigned*)&b23;
        *(uint2*)(buf + (rb + a * 16 + lr) * 144 + n * 32 + lk * 8) = w;
      }
  };
  auto pv = [&](char* buf, short8(&v)[2][4]) {
#pragma unroll
    for (int kb = 0; kb < 2; ++kb) {
      short8 pfA0 = *(const short8*)(buf + (0 + lr) * 144 + kb * 64 + lk * 16);
      short8 pfA1 = *(const short8*)(buf + (16 + lr) * 144 + kb * 64 + lk * 16);
      short8 pfB0 = *(const short8*)(buf + (32 + lr) * 144 + kb * 64 + lk * 16);
      short8 pfB1 = *(const short8*)(buf + (48 + lr) * 144 + kb * 64 + lk * 16);
#pragma unroll
      for (int nd = 0; nd < 4; ++nd) {
        oA[0][nd] = MFMA_BF16(pfA0, v[kb][nd], oA[0][nd]);
        oA[1][nd] = MFMA_BF16(pfA1, v[kb][nd], oA[1][nd]);
        oB[0][nd] = MFMA_BF16(pfB0, v[kb][nd], oB[0][nd]);
        oB[1][nd] = MFMA_BF16(pfB1, v[kb][nd], oB[1][nd]);
      }
      lsA[0] = MFMA_BF16(pfA0, vones, lsA[0]);
      lsA[1] = MFMA_BF16(pfA1, vones, lsA[1]);
      lsB[0] = MFMA_BF16(pfB0, vones, lsB[0]);
      lsB[1] = MFMA_BF16(pfB1, vones, lsB[1]);
    }
  };

  auto tile = [&](int i, bool diag, bool doPV,
                  short8(&kfc)[2][4], short8(&kfn)[2][4],
                  short8(&vp)[2][4], short8(&vc)[2][4],
                  char* bufp, char* bufc, int tnext) {
    loadK(kfn, tnext);
    loadV(vc, i);
    f32x4 stA[2][4] = {}, stB[2][4] = {};
#pragma unroll
    for (int kb = 0; kb < 2; ++kb)
#pragma unroll
      for (int a = 0; a < 2; ++a)
#pragma unroll
        for (int n = 0; n < 4; ++n) {
          stA[a][n] = MFMA_BF16(kfc[kb][n], qfA[a][kb], stA[a][n]);
          stB[a][n] = MFMA_BF16(kfc[kb][n], qfB[a][kb], stB[a][n]);
        }
    if (diag) {
#pragma unroll
      for (int a = 0; a < 2; ++a)
#pragma unroll
        for (int n = 0; n < 4; ++n)
#pragma unroll
          for (int r = 0; r < 4; ++r) {
            if (n * 16 + lk * 4 + r > 0 + a * 16 + lr) stA[a][n][r] = -3e38f;
            if (n * 16 + lk * 4 + r > 32 + a * 16 + lr) stB[a][n][r] = -3e38f;
          }
    }
    float pmA[2], pmB[2];
    rowmax(stA, pmA);
    rowmax(stB, pmB);
    float need = fmaxf(fmaxf(pmA[0] - mA[0], pmA[1] - mA[1]),
                       fmaxf(pmB[0] - mB[0], pmB[1] - mB[1]));
    if (doPV) pv(bufp, vp);
    if (__any(need > 8.f)) {
      rescale1(pmA, mA, lsA, oA);
      rescale1(pmB, mB, lsB, oB);
    }
    pack(stA, mA, bufc, 0);
    pack(stB, mB, bufc, 32);
  };

  short8 kf0[2][4], kf1[2][4], v0[2][4], v1[2][4];

  loadK(kf0, 0);
  tile(0, nt == 1, false, kf0, kf1, v1, v0, bufB, bufA, (1 < nt) ? 1 : 0);

  int i = 1;
  while (i < nt) {
    tile(i, i == nt - 1, true, kf1, kf0, v0, v1, bufA, bufB, (i + 1 < nt) ? i + 1 : i);
    if (++i >= nt) break;
    tile(i, i == nt - 1, true, kf0, kf1, v1, v0, bufB, bufA, (i + 1 < nt) ? i + 1 : i);
    ++i;
  }
  if ((nt - 1) & 1) pv(bufB, v1);
  else              pv(bufA, v0);

  const int b = bh >> 4, h2 = bh & 15;
#pragma unroll
  for (int a = 0; a < 2; ++a)
#pragma unroll
    for (int r = 0; r < 4; ++r) {
      float invA = 1.0f / lsA[a][r];
      float invB = 1.0f / lsB[a][r];
      int tA = q0 + a * 16 + lk * 4 + r;
      int tB = tA + 32;
#pragma unroll
      for (int nd = 0; nd < 4; ++nd) {
        ctx[((size_t)b * T_ + tA) * E_ + h2 * D_ + nd * 16 + lr] = f2bf(oA[a][nd][r] * invA);
        ctx[((size_t)b * T_ + tB) * E_ + h2 * D_ + nd * 16 + lr] = f2bf(oB[a][nd][r] * invB);
      }
    }
}

// ---------------- launcher ----------------
extern "C" void kernel_launch(void* const* d_in, const int* in_sizes, int n_in,
                              void* d_out, int out_size, void* d_ws, size_t ws_size,
                              hipStream_t stream) {
  const float* x    = (const float*)d_in[0];
  const float* Wq   = (const float*)d_in[1];
  const float* Wk   = (const float*)d_in[2];
  const float* Wv   = (const float*)d_in[3];
  const float* Wout = (const float*)d_in[4];
  const float* bout = (const float*)d_in[5];
  float* out = (float*)d_out;

  const size_t MT = (size_t)B_ * T_;      // 8192
  const size_t XE = MT * E_;              // 8,388,608
  const size_t WE = (size_t)E_ * E_;      // 1,048,576

  size_t need = (XE * 5 + WE * 4) * sizeof(unsigned short);
  if (ws_size < need) return;

  unsigned short* xb  = (unsigned short*)d_ws;
  unsigned short* wqb = xb + XE;
  unsigned short* wkb = wqb + WE;
  unsigned short* wvb = wkb + WE;
  unsigned short* wob = wvb + WE;
  unsigned short* Qb  = wob + WE;
  unsigned short* Kb  = Qb + XE;
  unsigned short* VTb = Kb + XE;
  unsigned short* ctx = VTb + XE;

  cvt_all<<<6144, 256, 0, stream>>>(x, Wq, Wk, Wv, Wout, xb, wqb);

  gemm_qkv8<<<384, 512, 0, stream>>>(xb, wqb, wkb, wvb, Qb, Kb, VTb);

  attn_fused<<<2048, 64, 0, stream>>>(Qb, Kb, VTb, ctx);

  gemm_out<<<512, 256, 0, stream>>>(ctx, wob, out, bout, (int)MT, E_, E_);
}

// Round 18
// 167.238 us; speedup vs baseline: 1.5477x; 1.1631x over previous
//
#include <hip/hip_runtime.h>
#include <hip/hip_bf16.h>
#include <stdint.h>
#include <math.h>

#define B_ 4
#define T_ 2048
#define E_ 1024
#define H_ 16
#define D_ 64

typedef __attribute__((ext_vector_type(8))) short short8;
typedef __attribute__((ext_vector_type(4))) short short4v;
typedef __attribute__((ext_vector_type(4))) float f32x4;

#define MFMA_BF16(a, b, c) __builtin_amdgcn_mfma_f32_16x16x32_bf16((a), (b), (c), 0, 0, 0)

__device__ __forceinline__ unsigned short f2bf(float f) {
  union { float f; unsigned u; } v; v.f = f;
  unsigned r = v.u + 0x7FFFu + ((v.u >> 16) & 1u);  // RNE
  return (unsigned short)(r >> 16);
}

#define GLOAD_LDS16(g, l)                                                        \
  __builtin_amdgcn_global_load_lds((const __attribute__((address_space(1))) void*)(g), \
                                   (__attribute__((address_space(3))) void*)(l), 16, 0, 0)

// ---------------- fp32 -> bf16 convert: x + 4 weights in ONE launch ----------
__global__ __launch_bounds__(256) void cvt_all(const float* __restrict__ x,
                                               const float* __restrict__ w0,
                                               const float* __restrict__ w1,
                                               const float* __restrict__ w2,
                                               const float* __restrict__ w3,
                                               unsigned short* __restrict__ xb,
                                               unsigned short* __restrict__ wb) {
  const int NX8 = 1048576;  // XE/8
  int i = blockIdx.x * blockDim.x + threadIdx.x;
  const float* src;
  unsigned short* dst;
  size_t off;
  if (i < NX8) {
    src = x; dst = xb; off = (size_t)i * 8;
  } else {
    int j = i - NX8;
    int which = j >> 17;             // WE/8 = 2^17
    int o = j & 131071;
    src = (which == 0) ? w0 : (which == 1) ? w1 : (which == 2) ? w2 : w3;
    dst = wb + ((size_t)which << 20);
    off = (size_t)o * 8;
  }
  const float4* p = (const float4*)(src + off);
  float4 a = p[0], b = p[1];
  short8 r;
  r[0] = (short)f2bf(a.x); r[1] = (short)f2bf(a.y);
  r[2] = (short)f2bf(a.z); r[3] = (short)f2bf(a.w);
  r[4] = (short)f2bf(b.x); r[5] = (short)f2bf(b.y);
  r[6] = (short)f2bf(b.z); r[7] = (short)f2bf(b.w);
  *(short8*)(dst + off) = r;
}

// =============== 128x256 2-phase pipelined GEMM template pieces ==============
// 512 thr (8 waves, 2M x 4N; per-wave 64x64). BK=64, LDS 96KB (2 x {A16K|B32K}).
// Full st_16x32 swizzle: stage pre-permutes global col (scol=8*((lane&7)^srow),
// row&7 invariant under +64-row strides); reads XOR (lr&7)<<4 -> 2-way (free).
// Schedule/K-tile: ph1 {ALL ds_reads; stageA(t+1); bar; lgkm0; 16 MFMA; bar}
//                  ph2 {stageB(t+2); 16 MFMA; vmcnt(4|0); bar}
// stageB(t+2) hits the buffer parity being read, but issues only after ph1's
// lgkm0+bar (all B(t) reads complete) -> no race. Steady outstanding:
// B(t+1)4 + A(t+1)2 + B(t+2)4 -> vmcnt(4) drains A/B(t+1).

#define GEMM2_BODY(A_PTR, B_PTR)                                                  \
  const int K = E_;                                                               \
  const int NT = 16;                                                              \
  const int tid = threadIdx.x;                                                    \
  const int wid = tid >> 6;                                                       \
  const int lane = tid & 63;                                                      \
  const int lr = lane & 15;                                                       \
  const int lk = lane >> 4;                                                       \
  const int wm = wid >> 2, wn = wid & 3;                                          \
  const int srow = lane >> 3;                                                     \
  const int scol = ((lane & 7) ^ srow) * 8;                                       \
  const int rswz = (lr & 7) << 4;                                                 \
  const int kofs0 = (lk * 16) ^ rswz;                                             \
  const int kofs1 = (64 + lk * 16) ^ rswz;                                        \
  f32x4 acc[4][4] = {};                                                           \
  short8 af[4][2], bf0[2][2], bf1[2][2];                                          \
  auto stageA = [&](int tau) {                                                    \
    char* dst = lds + (tau & 1) * 49152 + wid * 1024;                             \
    const unsigned short* src = (A_PTR) + (size_t)(m0 + wid * 8 + srow) * K +     \
                                tau * 64 + scol;                                  \
    GLOAD_LDS16(src, dst);                                                        \
    GLOAD_LDS16(src + (size_t)64 * K, dst + 8192);                                \
  };                                                                              \
  auto stageB = [&](int tau) {                                                    \
    char* dst = lds + (tau & 1) * 49152 + 16384 + wid * 1024;                     \
    const unsigned short* src = (B_PTR) + (size_t)(n0 + wid * 8 + srow) * K +     \
                                tau * 64 + scol;                                  \
    GLOAD_LDS16(src, dst);                                                        \
    GLOAD_LDS16(src + (size_t)64 * K, dst + 8192);                                \
    GLOAD_LDS16(src + (size_t)128 * K, dst + 16384);                              \
    GLOAD_LDS16(src + (size_t)192 * K, dst + 24576);                              \
  };                                                                              \
  stageB(0); stageA(0); stageB(1);                                                \
  asm volatile("s_waitcnt vmcnt(4)" ::: "memory");                                \
  __builtin_amdgcn_s_barrier();                                                   \
  for (int t = 0; t < NT; ++t) {                                                  \
    char* bufA = lds + (t & 1) * 49152;                                           \
    char* bufB = bufA + 16384;                                                    \
    _Pragma("unroll")                                                             \
    for (int i = 0; i < 4; ++i) {                                                 \
      int row = wm * 64 + i * 16 + lr;                                            \
      af[i][0] = *(const short8*)(bufA + row * 128 + kofs0);                      \
      af[i][1] = *(const short8*)(bufA + row * 128 + kofs1);                      \
    }                                                                             \
    _Pragma("unroll")                                                             \
    for (int i = 0; i < 2; ++i) {                                                 \
      int row0 = wn * 64 + i * 16 + lr;                                           \
      int row1 = wn * 64 + (2 + i) * 16 + lr;                                     \
      bf0[i][0] = *(const short8*)(bufB + row0 * 128 + kofs0);                    \
      bf0[i][1] = *(const short8*)(bufB + row0 * 128 + kofs1);                    \
      bf1[i][0] = *(const short8*)(bufB + row1 * 128 + kofs0);                    \
      bf1[i][1] = *(const short8*)(bufB + row1 * 128 + kofs1);                    \
    }                                                                             \
    if (t + 1 < NT) stageA(t + 1);                                                \
    __builtin_amdgcn_s_barrier();                                                 \
    asm volatile("s_waitcnt lgkmcnt(0)" ::: "memory");                            \
    __builtin_amdgcn_sched_barrier(0);                                            \
    __builtin_amdgcn_s_setprio(1);                                                \
    _Pragma("unroll")                                                             \
    for (int i = 0; i < 4; ++i)                                                   \
      _Pragma("unroll")                                                           \
      for (int jn = 0; jn < 2; ++jn) {                                            \
        acc[i][jn] = MFMA_BF16(af[i][0], bf0[jn][0], acc[i][jn]);                 \
        acc[i][jn] = MFMA_BF16(af[i][1], bf0[jn][1], acc[i][jn]);                 \
      }                                                                           \
    __builtin_amdgcn_s_setprio(0);                                                \
    __builtin_amdgcn_s_barrier();                                                 \
    if (t + 2 < NT) stageB(t + 2);                                                \
    __builtin_amdgcn_s_setprio(1);                                                \
    _Pragma("unroll")                                                             \
    for (int i = 0; i < 4; ++i)                                                   \
      _Pragma("unroll")                                                           \
      for (int jn = 0; jn < 2; ++jn) {                                            \
        acc[i][2 + jn] = MFMA_BF16(af[i][0], bf1[jn][0], acc[i][2 + jn]);         \
        acc[i][2 + jn] = MFMA_BF16(af[i][1], bf1[jn][1], acc[i][2 + jn]);         \
      }                                                                           \
    __builtin_amdgcn_s_setprio(0);                                                \
    if (t < NT - 2) asm volatile("s_waitcnt vmcnt(4)" ::: "memory");              \
    else            asm volatile("s_waitcnt vmcnt(0)" ::: "memory");              \
    __builtin_amdgcn_s_barrier();                                                 \
  }

// ---------------- QKV GEMM (768 blocks = 3 exact rounds at 1 blk/CU) ---------
// sel 0/1 (Q,K): bf16 [B*H][T][D]; sel 2 (V): bf16 transposed [B*H][D][T].
__global__ __launch_bounds__(512) void gemm_qkv2(const unsigned short* __restrict__ A,
                                                 const unsigned short* __restrict__ Wq,
                                                 const unsigned short* __restrict__ Wk,
                                                 const unsigned short* __restrict__ Wv,
                                                 unsigned short* __restrict__ Qo,
                                                 unsigned short* __restrict__ Ko,
                                                 unsigned short* __restrict__ Vo) {
  __shared__ __align__(16) char lds[98304];
  const int bid = blockIdx.x;
  const int xcd = bid & 7;
  const int p = bid >> 3;               // 0..95
  const int m0 = (xcd * 8 + (p & 7)) * 128;
  const int j = p >> 3;                 // 0..11
  const int n0 = (j & 3) * 256;
  const int sel = j >> 2;
  const unsigned short* Bm = (sel == 0) ? Wq : (sel == 1) ? Wk : Wv;

  GEMM2_BODY(A, Bm)

  unsigned short* outp = (sel == 0) ? Qo : (sel == 1) ? Ko : Vo;
#pragma unroll
  for (int mi = 0; mi < 4; ++mi)
#pragma unroll
    for (int ni = 0; ni < 4; ++ni) {
      int row0 = m0 + wm * 64 + mi * 16 + lk * 4;
      int col = n0 + wn * 64 + ni * 16 + lr;
      int b = row0 >> 11, t0 = row0 & (T_ - 1), h = col >> 6, d = col & (D_ - 1);
      if (sel == 2) {
        short4v vv;
#pragma unroll
        for (int r = 0; r < 4; ++r) vv[r] = (short)f2bf(acc[mi][ni][r]);
        *(short4v*)&outp[(((size_t)(b * H_ + h)) * D_ + d) * T_ + t0] = vv;  // [BH][D][T]
      } else {
#pragma unroll
        for (int r = 0; r < 4; ++r)
          outp[(((size_t)(b * H_ + h)) * T_ + t0 + r) * D_ + d] = f2bf(acc[mi][ni][r]);
      }
    }
}

// ---------------- out-proj GEMM (256 blocks = exactly 1/CU) ------------------
__global__ __launch_bounds__(512) void gemm_out2(const unsigned short* __restrict__ A,
                                                 const unsigned short* __restrict__ Wout,
                                                 float* __restrict__ outp,
                                                 const float* __restrict__ bias) {
  __shared__ __align__(16) char lds[98304];
  const int bid = blockIdx.x;
  const int xcd = bid & 7;
  const int p = bid >> 3;               // 0..31
  const int m0 = (xcd * 8 + (p & 7)) * 128;
  const int n0 = (p >> 3) * 256;

  GEMM2_BODY(A, Wout)

#pragma unroll
  for (int mi = 0; mi < 4; ++mi)
#pragma unroll
    for (int ni = 0; ni < 4; ++ni) {
      int row0 = m0 + wm * 64 + mi * 16 + lk * 4;
      int col = n0 + wn * 64 + ni * 16 + lr;
      float bv = bias[col];
#pragma unroll
      for (int r = 0; r < 4; ++r)
        outp[(size_t)(row0 + r) * E_ + col] = acc[mi][ni][r] + bv;
    }
}

// ---------------- fused causal flash attention (r11 body, verbatim) ----------
__global__ __launch_bounds__(64) void attn_fused(const unsigned short* __restrict__ Q,
                                                 const unsigned short* __restrict__ K,
                                                 const unsigned short* __restrict__ VT,
                                                 unsigned short* __restrict__ ctx) {
  __shared__ __align__(16) unsigned short Pl[2][64 * 72];
  const int lane = threadIdx.x & 63;
  const int lr = lane & 15;
  const int lk = lane >> 4;

  const int bid = blockIdx.x;
  const int xcd = bid & 7;
  const int p = bid >> 3;
  const int bh = xcd * 8 + (p & 7);
  const int c = 31 - (p >> 3);
  const int q0 = c * 64;

  const unsigned short* Qh = Q + (size_t)bh * T_ * D_;
  const unsigned short* Kh = K + (size_t)bh * T_ * D_;
  const unsigned short* Vh = VT + (size_t)bh * T_ * D_;
  char* bufA = (char*)&Pl[0][0];
  char* bufB = (char*)&Pl[1][0];

  const float SC = 0.125f * 1.44269504089f;

  short8 vones;
#pragma unroll
  for (int j = 0; j < 8; ++j) vones[j] = (short)0x3F80;

  short8 qfA[2][2], qfB[2][2];
#pragma unroll
  for (int a = 0; a < 2; ++a)
#pragma unroll
    for (int kb = 0; kb < 2; ++kb) {
      qfA[a][kb] = *(const short8*)&Qh[(size_t)(q0 + a * 16 + lr) * D_ + kb * 32 + lk * 8];
      qfB[a][kb] = *(const short8*)&Qh[(size_t)(q0 + 32 + a * 16 + lr) * D_ + kb * 32 + lk * 8];
    }

  f32x4 oA[2][4] = {}, oB[2][4] = {};
  f32x4 lsA[2] = {}, lsB[2] = {};
  float mA[2] = {-1e30f, -1e30f}, mB[2] = {-1e30f, -1e30f};

  const int nt = c + 1;

  auto loadK = [&](short8(&kf)[2][4], int t) {
    const unsigned short* Kt = Kh + (size_t)t * 64 * D_;
#pragma unroll
    for (int kb = 0; kb < 2; ++kb)
#pragma unroll
      for (int n = 0; n < 4; ++n)
        kf[kb][n] = *(const short8*)&Kt[(size_t)(n * 16 + lr) * D_ + kb * 32 + lk * 8];
  };
  auto loadV = [&](short8(&v)[2][4], int t) {
    const unsigned short* Vtt = Vh + (size_t)t * 64;
#pragma unroll
    for (int kb = 0; kb < 2; ++kb)
#pragma unroll
      for (int nd = 0; nd < 4; ++nd)
        v[kb][nd] = *(const short8*)&Vtt[(size_t)(nd * 16 + lr) * T_ + kb * 32 + lk * 8];
  };
  auto rowmax = [&](f32x4(&st)[2][4], float(&pm)[2]) {
#pragma unroll
    for (int a = 0; a < 2; ++a) {
      float m0 = fmaxf(fmaxf(st[a][0][0], st[a][1][0]), fmaxf(st[a][2][0], st[a][3][0]));
      float m1 = fmaxf(fmaxf(st[a][0][1], st[a][1][1]), fmaxf(st[a][2][1], st[a][3][1]));
      float m2 = fmaxf(fmaxf(st[a][0][2], st[a][1][2]), fmaxf(st[a][2][2], st[a][3][2]));
      float m3 = fmaxf(fmaxf(st[a][0][3], st[a][1][3]), fmaxf(st[a][2][3], st[a][3][3]));
      float mx = fmaxf(fmaxf(m0, m1), fmaxf(m2, m3));
      mx = fmaxf(mx, __shfl_xor(mx, 16));
      mx = fmaxf(mx, __shfl_xor(mx, 32));
      pm[a] = mx * SC;
    }
  };
  auto rescale1 = [&](float(&pm)[2], float(&mrun)[2], f32x4(&ls)[2], f32x4(&o)[2][4]) {
#pragma unroll
    for (int a = 0; a < 2; ++a) {
      float mnew = fmaxf(mrun[a], pm[a]);
      float sc = exp2f(mrun[a] - mnew);
      mrun[a] = mnew;
#pragma unroll
      for (int r = 0; r < 4; ++r) {
        float sco = __shfl(sc, (lane & 48) | (lk * 4 + r));
        ls[a][r] *= sco;
#pragma unroll
        for (int nd = 0; nd < 4; ++nd) o[a][nd][r] *= sco;
      }
    }
  };
  auto pack = [&](f32x4(&st)[2][4], float(&mrun)[2], char* buf, int rb) {
#pragma unroll
    for (int a = 0; a < 2; ++a)
#pragma unroll
      for (int n = 0; n < 4; ++n) {
        float2 p01, p23;
        p01.x = exp2f(fmaf(st[a][n][0], SC, -mrun[a]));
        p01.y = exp2f(fmaf(st[a][n][1], SC, -mrun[a]));
        p23.x = exp2f(fmaf(st[a][n][2], SC, -mrun[a]));
        p23.y = exp2f(fmaf(st[a][n][3], SC, -mrun[a]));
        __hip_bfloat162 b01 = __float22bfloat162_rn(p01);
        __hip_bfloat162 b23 = __float22bfloat162_rn(p23);
        uint2 w;
        w.x = *(unsigned*)&b01;
        w.y = *(unsigned*)&b23;
        *(uint2*)(buf + (rb + a * 16 + lr) * 144 + n * 32 + lk * 8) = w;
      }
  };
  auto pv = [&](char* buf, short8(&v)[2][4]) {
#pragma unroll
    for (int kb = 0; kb < 2; ++kb) {
      short8 pfA0 = *(const short8*)(buf + (0 + lr) * 144 + kb * 64 + lk * 16);
      short8 pfA1 = *(const short8*)(buf + (16 + lr) * 144 + kb * 64 + lk * 16);
      short8 pfB0 = *(const short8*)(buf + (32 + lr) * 144 + kb * 64 + lk * 16);
      short8 pfB1 = *(const short8*)(buf + (48 + lr) * 144 + kb * 64 + lk * 16);
#pragma unroll
      for (int nd = 0; nd < 4; ++nd) {
        oA[0][nd] = MFMA_BF16(pfA0, v[kb][nd], oA[0][nd]);
        oA[1][nd] = MFMA_BF16(pfA1, v[kb][nd], oA[1][nd]);
        oB[0][nd] = MFMA_BF16(pfB0, v[kb][nd], oB[0][nd]);
        oB[1][nd] = MFMA_BF16(pfB1, v[kb][nd], oB[1][nd]);
      }
      lsA[0] = MFMA_BF16(pfA0, vones, lsA[0]);
      lsA[1] = MFMA_BF16(pfA1, vones, lsA[1]);
      lsB[0] = MFMA_BF16(pfB0, vones, lsB[0]);
      lsB[1] = MFMA_BF16(pfB1, vones, lsB[1]);
    }
  };

  auto tile = [&](int i, bool diag, bool doPV,
                  short8(&kfc)[2][4], short8(&kfn)[2][4],
                  short8(&vp)[2][4], short8(&vc)[2][4],
                  char* bufp, char* bufc, int tnext) {
    loadK(kfn, tnext);
    loadV(vc, i);
    f32x4 stA[2][4] = {}, stB[2][4] = {};
#pragma unroll
    for (int kb = 0; kb < 2; ++kb)
#pragma unroll
      for (int a = 0; a < 2; ++a)
#pragma unroll
        for (int n = 0; n < 4; ++n) {
          stA[a][n] = MFMA_BF16(kfc[kb][n], qfA[a][kb], stA[a][n]);
          stB[a][n] = MFMA_BF16(kfc[kb][n], qfB[a][kb], stB[a][n]);
        }
    if (diag) {
#pragma unroll
      for (int a = 0; a < 2; ++a)
#pragma unroll
        for (int n = 0; n < 4; ++n)
#pragma unroll
          for (int r = 0; r < 4; ++r) {
            if (n * 16 + lk * 4 + r > 0 + a * 16 + lr) stA[a][n][r] = -3e38f;
            if (n * 16 + lk * 4 + r > 32 + a * 16 + lr) stB[a][n][r] = -3e38f;
          }
    }
    float pmA[2], pmB[2];
    rowmax(stA, pmA);
    rowmax(stB, pmB);
    float need = fmaxf(fmaxf(pmA[0] - mA[0], pmA[1] - mA[1]),
                       fmaxf(pmB[0] - mB[0], pmB[1] - mB[1]));
    if (doPV) pv(bufp, vp);
    if (__any(need > 8.f)) {
      rescale1(pmA, mA, lsA, oA);
      rescale1(pmB, mB, lsB, oB);
    }
    pack(stA, mA, bufc, 0);
    pack(stB, mB, bufc, 32);
  };

  short8 kf0[2][4], kf1[2][4], v0[2][4], v1[2][4];

  loadK(kf0, 0);
  tile(0, nt == 1, false, kf0, kf1, v1, v0, bufB, bufA, (1 < nt) ? 1 : 0);

  int i = 1;
  while (i < nt) {
    tile(i, i == nt - 1, true, kf1, kf0, v0, v1, bufA, bufB, (i + 1 < nt) ? i + 1 : i);
    if (++i >= nt) break;
    tile(i, i == nt - 1, true, kf0, kf1, v1, v0, bufB, bufA, (i + 1 < nt) ? i + 1 : i);
    ++i;
  }
  if ((nt - 1) & 1) pv(bufB, v1);
  else              pv(bufA, v0);

  const int b = bh >> 4, h2 = bh & 15;
#pragma unroll
  for (int a = 0; a < 2; ++a)
#pragma unroll
    for (int r = 0; r < 4; ++r) {
      float invA = 1.0f / lsA[a][r];
      float invB = 1.0f / lsB[a][r];
      int tA = q0 + a * 16 + lk * 4 + r;
      int tB = tA + 32;
#pragma unroll
      for (int nd = 0; nd < 4; ++nd) {
        ctx[((size_t)b * T_ + tA) * E_ + h2 * D_ + nd * 16 + lr] = f2bf(oA[a][nd][r] * invA);
        ctx[((size_t)b * T_ + tB) * E_ + h2 * D_ + nd * 16 + lr] = f2bf(oB[a][nd][r] * invB);
      }
    }
}

// ---------------- launcher ----------------
extern "C" void kernel_launch(void* const* d_in, const int* in_sizes, int n_in,
                              void* d_out, int out_size, void* d_ws, size_t ws_size,
                              hipStream_t stream) {
  const float* x    = (const float*)d_in[0];
  const float* Wq   = (const float*)d_in[1];
  const float* Wk   = (const float*)d_in[2];
  const float* Wv   = (const float*)d_in[3];
  const float* Wout = (const float*)d_in[4];
  const float* bout = (const float*)d_in[5];
  float* out = (float*)d_out;

  const size_t MT = (size_t)B_ * T_;      // 8192
  const size_t XE = MT * E_;              // 8,388,608
  const size_t WE = (size_t)E_ * E_;      // 1,048,576

  size_t need = (XE * 5 + WE * 4) * sizeof(unsigned short);
  if (ws_size < need) return;

  unsigned short* xb  = (unsigned short*)d_ws;
  unsigned short* wqb = xb + XE;
  unsigned short* wkb = wqb + WE;
  unsigned short* wvb = wkb + WE;
  unsigned short* wob = wvb + WE;
  unsigned short* Qb  = wob + WE;
  unsigned short* Kb  = Qb + XE;
  unsigned short* VTb = Kb + XE;
  unsigned short* ctx = VTb + XE;

  cvt_all<<<6144, 256, 0, stream>>>(x, Wq, Wk, Wv, Wout, xb, wqb);

  gemm_qkv2<<<768, 512, 0, stream>>>(xb, wqb, wkb, wvb, Qb, Kb, VTb);

  attn_fused<<<2048, 64, 0, stream>>>(Qb, Kb, VTb, ctx);

  gemm_out2<<<256, 512, 0, stream>>>(ctx, wob, out, bout);
}